// Round 2
// baseline (1022.992 us; speedup 1.0000x reference)
//
#include <hip/hip_runtime.h>
#include <hip/hip_bf16.h>
#include <stdint.h>

typedef __hip_bfloat16 bf16;
typedef __attribute__((ext_vector_type(8))) short short8;
typedef __attribute__((ext_vector_type(4))) float floatx4;
typedef __attribute__((address_space(3))) const unsigned short lu16;

// ---------- helpers ----------
__device__ __forceinline__ float ldf(const float* p) { return *p; }
__device__ __forceinline__ float ldf(const bf16* p) { return __bfloat162float(*p); }

__device__ __forceinline__ unsigned short f2bu(float f) {
  bf16 b = __float2bfloat16(f);
  return *reinterpret_cast<unsigned short*>(&b);
}

// non-temporal C-writes: keep streaming GEMM output from evicting A/B in L2/L3
__device__ __forceinline__ void stnt(float* p, float v) { __builtin_nontemporal_store(v, p); }
__device__ __forceinline__ void stnt(bf16* p, float v) {
  __builtin_nontemporal_store(f2bu(v), (unsigned short*)p);
}

// vectorized 4-element loads -> f32 lanes
__device__ __forceinline__ void ld4(const float* p, float* o) {
  float4 v = *(const float4*)p;
  o[0] = v.x; o[1] = v.y; o[2] = v.z; o[3] = v.w;
}
__device__ __forceinline__ void ld4(const bf16* p, float* o) {
  ushort4 v = *(const ushort4*)p;
  o[0] = __bfloat162float(*(bf16*)&v.x);
  o[1] = __bfloat162float(*(bf16*)&v.y);
  o[2] = __bfloat162float(*(bf16*)&v.z);
  o[3] = __bfloat162float(*(bf16*)&v.w);
}

// async global->LDS, 16B per lane; lds base wave-uniform, HW writes base + lane*16
__device__ __forceinline__ void gl_lds16(const bf16* g, bf16* l) {
  __builtin_amdgcn_global_load_lds((const __attribute__((address_space(1))) void*)g,
                                   (__attribute__((address_space(3))) void*)l,
                                   16, 0, 0);
}

// inline-asm ds_read_b128 with compile-time byte offset
template <int OFF>
__device__ __forceinline__ short8 ldsro(lu16* p) {
  short8 r;
  asm volatile("ds_read_b128 %0, %1 offset:%2" : "=v"(r) : "v"(p), "i"(OFF));
  return r;
}

#define BAR() __builtin_amdgcn_s_barrier()
#define LGKM0() do { asm volatile("s_waitcnt lgkmcnt(0)" ::: "memory"); \
                     __builtin_amdgcn_sched_barrier(0); } while (0)
#define VMCNT(n) asm volatile("s_waitcnt vmcnt(" #n ")" ::: "memory")

// ---------- conversions ----------
__global__ void cvt_f32_bf16(const float* __restrict__ in, bf16* __restrict__ out, long n4) {
  long i = (long)blockIdx.x * blockDim.x + threadIdx.x;
  if (i >= n4) return;
  float4 v = ((const float4*)in)[i];
  ushort4 o;
  o.x = f2bu(v.x); o.y = f2bu(v.y); o.z = f2bu(v.z); o.w = f2bu(v.w);
  ((ushort4*)out)[i] = o;
}

// in: [R][Cc] f32 -> out: [Cc][R] bf16   (R, Cc multiples of 32)
__global__ void transpose_f32_to_bf16(const float* __restrict__ in, bf16* __restrict__ out,
                                      int R, int Cc) {
  __shared__ float tile[32][33];
  int tx = threadIdx.x & 31;
  int ty = threadIdx.x >> 5;  // 0..7
  int c0 = blockIdx.x * 32;
  int r0 = blockIdx.y * 32;
#pragma unroll
  for (int i = 0; i < 32; i += 8)
    tile[ty + i][tx] = in[(long)(r0 + ty + i) * Cc + c0 + tx];
  __syncthreads();
#pragma unroll
  for (int i = 0; i < 32; i += 8)
    out[(long)(c0 + ty + i) * R + r0 + tx] = __float2bfloat16(tile[tx][ty + i]);
}

// ---------- GEMM: C[M][N] = A[M][K] * BT[N][K]^T, bf16 in, OUT_T out ----------
// 256x256 tile, BK=64, 512 threads = 8 waves (2M x 4N), mfma_f32_16x16x32_bf16.
// 8-phase schedule, counted vmcnt(4) at phases 4/8, LDS XOR swizzle (16B slot
// c8 of row r at phys c8 ^ (r&7); staging pre-swizzles the global source).
// Requires M%256==0, N%256==0, K%128==0, gridDim.x%8==0.
template <typename OUT_T>
__global__ __launch_bounds__(512, 2) void gemm256(const bf16* __restrict__ A,
                                                  const bf16* __restrict__ BT,
                                                  OUT_T* __restrict__ C,
                                                  int M, int N, int K) {
  __shared__ __align__(16) bf16 lds[2][2][256][64];  // [buf][A/B][row][k] = 128 KiB

  const int tid = threadIdx.x;
  const int w = tid >> 6;
  const int lane = tid & 63;
  const int quad = lane >> 4;
  const int r16 = lane & 15;
  const int wm = (w >> 2) * 128;  // wave row block
  const int wn = (w & 3) * 64;    // wave col block

  // XCD-bijective swizzle (T1): gridDim.x % 8 == 0
  const int nbx = N >> 8;
  const int nwg = nbx * (M >> 8);
  const int bid = blockIdx.x;
  const int swz = (bid & 7) * (nwg >> 3) + (bid >> 3);
  const long bM = (long)(swz / nbx) * 256;
  const long bN = (long)(swz % nbx) * 256;

  // staging per-lane source coords
  const int r0 = tid >> 3;                       // 0..63 (i=1 adds 64 rows)
  const int c8 = (tid & 7) ^ (r0 & 7);
  const bf16* Ag = A + (bM + r0) * (long)K + c8 * 8;
  const bf16* Bg = BT + (bN + r0) * (long)K + c8 * 8;
  const int lslot = w * 512;                     // wave-uniform LDS elem base

  bf16* Am0 = &lds[0][0][0][0];
  bf16* Am1 = &lds[1][0][0][0];
  bf16* Bm0 = &lds[0][1][0][0];
  bf16* Bm1 = &lds[1][1][0][0];

  auto stage = [&](const bf16* g, bf16* lmat, int half, int kt) {
    const bf16* gs = g + (long)half * 128 * K + (long)kt * 64;
    bf16* ls = lmat + half * 8192 + lslot;
    gl_lds16(gs, ls);
    gl_lds16(gs + 64L * K, ls + 4096);
  };

  // fragment read bases (AS3, swizzled)
  const int lofsA = (wm + r16) * 64;
  const int lofsB = (wn + r16) * 64;
  const int c8x0 = ((0 * 4 + quad) ^ (r16 & 7)) * 8;
  const int c8x1 = ((1 * 4 + quad) ^ (r16 & 7)) * 8;
  lu16* lb = (lu16*)&lds[0][0][0][0];
  lu16* pA0k0 = lb + 0 * 32768 + 0 * 16384 + lofsA + c8x0;
  lu16* pA0k1 = lb + 0 * 32768 + 0 * 16384 + lofsA + c8x1;
  lu16* pA1k0 = lb + 1 * 32768 + 0 * 16384 + lofsA + c8x0;
  lu16* pA1k1 = lb + 1 * 32768 + 0 * 16384 + lofsA + c8x1;
  lu16* pB0k0 = lb + 0 * 32768 + 1 * 16384 + lofsB + c8x0;
  lu16* pB0k1 = lb + 0 * 32768 + 1 * 16384 + lofsB + c8x1;
  lu16* pB1k0 = lb + 1 * 32768 + 1 * 16384 + lofsB + c8x0;
  lu16* pB1k1 = lb + 1 * 32768 + 1 * 16384 + lofsB + c8x1;

  floatx4 acc[8][4];
#pragma unroll
  for (int a = 0; a < 8; a++)
#pragma unroll
    for (int b = 0; b < 4; b++) acc[a][b] = (floatx4){0.f, 0.f, 0.f, 0.f};

  short8 af[4][2], bq0[2][2], bq1[2][2];

#define READ_A(P0, P1, MG) do { \
  af[0][0] = ldsro<((MG)*4 + 0) * 2048>(P0); af[0][1] = ldsro<((MG)*4 + 0) * 2048>(P1); \
  af[1][0] = ldsro<((MG)*4 + 1) * 2048>(P0); af[1][1] = ldsro<((MG)*4 + 1) * 2048>(P1); \
  af[2][0] = ldsro<((MG)*4 + 2) * 2048>(P0); af[2][1] = ldsro<((MG)*4 + 2) * 2048>(P1); \
  af[3][0] = ldsro<((MG)*4 + 3) * 2048>(P0); af[3][1] = ldsro<((MG)*4 + 3) * 2048>(P1); \
} while (0)

#define READ_B(P0, P1, NG, BQ) do { \
  BQ[0][0] = ldsro<((NG)*2 + 0) * 2048>(P0); BQ[0][1] = ldsro<((NG)*2 + 0) * 2048>(P1); \
  BQ[1][0] = ldsro<((NG)*2 + 1) * 2048>(P0); BQ[1][1] = ldsro<((NG)*2 + 1) * 2048>(P1); \
} while (0)

#define PH_MMA(MG, NG, BQ) do { \
  __builtin_amdgcn_s_setprio(1); \
  _Pragma("unroll") \
  for (int mf = 0; mf < 4; ++mf) \
    _Pragma("unroll") \
    for (int nf = 0; nf < 2; ++nf) { \
      acc[(MG)*4 + mf][(NG)*2 + nf] = __builtin_amdgcn_mfma_f32_16x16x32_bf16( \
          af[mf][0], BQ[nf][0], acc[(MG)*4 + mf][(NG)*2 + nf], 0, 0, 0); \
      acc[(MG)*4 + mf][(NG)*2 + nf] = __builtin_amdgcn_mfma_f32_16x16x32_bf16( \
          af[mf][1], BQ[nf][1], acc[(MG)*4 + mf][(NG)*2 + nf], 0, 0, 0); \
    } \
  __builtin_amdgcn_s_setprio(0); \
} while (0)

#define KTILE(PA0, PA1, PB0, PB1, S1, S2, S3, S4, VMX) do { \
  READ_A(PA0, PA1, 0); READ_B(PB0, PB1, 0, bq0); S1; \
  BAR(); LGKM0(); PH_MMA(0, 0, bq0); BAR(); \
  READ_B(PB0, PB1, 1, bq1); S2; \
  BAR(); LGKM0(); PH_MMA(0, 1, bq1); BAR(); \
  READ_A(PA0, PA1, 1); S3; \
  BAR(); LGKM0(); PH_MMA(1, 1, bq1); BAR(); \
  S4; BAR(); PH_MMA(1, 0, bq0); VMX; BAR(); \
} while (0)

  // prologue: tile0 -> buf0, tile1 B -> buf1; drain tile0
  stage(Ag, Am0, 0, 0); stage(Ag, Am0, 1, 0);
  stage(Bg, Bm0, 0, 0); stage(Bg, Bm0, 1, 0);
  stage(Bg, Bm1, 0, 1); stage(Bg, Bm1, 1, 1);
  VMCNT(4);
  BAR();

  const int NI = K >> 7;
  for (int i = 0; i < NI - 1; ++i) {
    const int k1 = 2 * i + 1, k2 = 2 * i + 2, k3 = 2 * i + 3;
    KTILE(pA0k0, pA0k1, pB0k0, pB0k1,
          stage(Ag, Am1, 0, k1), stage(Ag, Am1, 1, k1),
          stage(Bg, Bm0, 0, k2), stage(Bg, Bm0, 1, k2), VMCNT(4));
    KTILE(pA1k0, pA1k1, pB1k0, pB1k1,
          stage(Ag, Am0, 0, k2), stage(Ag, Am0, 1, k2),
          stage(Bg, Bm1, 0, k3), stage(Bg, Bm1, 1, k3), VMCNT(4));
  }
  {
    const int kl = 2 * NI - 1;
    KTILE(pA0k0, pA0k1, pB0k0, pB0k1,
          stage(Ag, Am1, 0, kl), stage(Ag, Am1, 1, kl),
          (void)0, (void)0, VMCNT(0));
    KTILE(pA1k0, pA1k1, pB1k0, pB1k1,
          (void)0, (void)0, (void)0, (void)0, (void)0);
  }

#undef KTILE
#undef PH_MMA
#undef READ_B
#undef READ_A

  // C/D layout: col = lane&15, row = quad*4 + reg  -- non-temporal stores
#pragma unroll
  for (int mf = 0; mf < 8; ++mf) {
#pragma unroll
    for (int i2 = 0; i2 < 4; ++i2) {
      long row = bM + wm + mf * 16 + quad * 4 + i2;
      OUT_T* crow = C + row * (long)N + bN + wn + r16;
#pragma unroll
      for (int nf = 0; nf < 4; ++nf) stnt(&crow[nf * 16], acc[mf][nf][i2]);
    }
  }
}

// ---------- scan ----------
// c = sigmoid(-gate), v = sigmoid(gate) * g(hidden); g(x) = x>=0 ? x+0.5 : sigmoid(x)
__device__ __forceinline__ void cv_compute(float hval, float gval, float& c, float& v) {
  float eg = __expf(gval);
  c = 1.f / (1.f + eg);
  float z = 1.f - c;
  float gx = (hval >= 0.f) ? (hval + 0.5f) : (1.f / (1.f + __expf(-hval)));
  v = z * gx;
}

// pass1: per (b, chunk, e-quad): P = prod c, V = local recurrence from 0 (4 lanes/thread)
template <typename T>
__global__ void scan_pass1(const T* __restrict__ hg, float* __restrict__ P,
                           float* __restrict__ V, int S, int Di, int NN, int nch) {
  int tid = blockIdx.x * blockDim.x + threadIdx.x;  // over B*nch*(Di/4)
  int De = Di >> 2;
  int e = (tid % De) * 4;
  int rest = tid / De;
  int ch = rest % nch;
  int b = rest / nch;
  int CH = S / nch;
  const T* ph = hg + ((long)(b * S + ch * CH)) * NN + e;
  float Pv[4] = {1.f, 1.f, 1.f, 1.f}, Vv[4] = {0.f, 0.f, 0.f, 0.f};
  for (int t = 0; t < CH; t++) {
    float hv[4], gv[4];
    ld4(ph, hv);
    ld4(ph + Di, gv);
#pragma unroll
    for (int j = 0; j < 4; j++) {
      float c, v;
      cv_compute(hv[j], gv[j], c, v);
      Pv[j] *= c;
      Vv[j] = fmaf(c, Vv[j], v);
    }
    ph += NN;
  }
  long base = ((long)(b * nch + ch)) * Di + e;
  *(float4*)&P[base] = make_float4(Pv[0], Pv[1], Pv[2], Pv[3]);
  *(float4*)&V[base] = make_float4(Vv[0], Vv[1], Vv[2], Vv[3]);
}

// pass2: scan the chunk summaries, store carry-in per chunk
__global__ void scan_pass2(const float* __restrict__ P, const float* __restrict__ V,
                           float* __restrict__ Hc, int Di, int nch) {
  int tid = blockIdx.x * blockDim.x + threadIdx.x;  // b*Di + e
  int e = tid % Di;
  int b = tid / Di;
  float H = 0.f;
  for (int j = 0; j < nch; j++) {
    long idx = ((long)(b * nch + j)) * Di + e;
    Hc[idx] = H;
    H = fmaf(P[idx], H, V[idx]);
  }
}

// pass3: replay chunk with carry, write h (bf16), 4 lanes/thread
template <typename T>
__global__ void scan_pass3(const T* __restrict__ hg, const float* __restrict__ Hc,
                           bf16* __restrict__ h, int S, int Di, int NN, int nch) {
  int tid = blockIdx.x * blockDim.x + threadIdx.x;  // over B*nch*(Di/4)
  int De = Di >> 2;
  int e = (tid % De) * 4;
  int rest = tid / De;
  int ch = rest % nch;
  int b = rest / nch;
  int CH = S / nch;
  const T* ph = hg + ((long)(b * S + ch * CH)) * NN + e;
  bf16* po = h + ((long)(b * S + ch * CH)) * Di + e;
  long base = ((long)(b * nch + ch)) * Di + e;
  float4 hc = *(const float4*)&Hc[base];
  float H[4] = {hc.x, hc.y, hc.z, hc.w};
  for (int t = 0; t < CH; t++) {
    float hv[4], gv[4];
    ld4(ph, hv);
    ld4(ph + Di, gv);
    ushort4 o;
#pragma unroll
    for (int j = 0; j < 4; j++) {
      float c, v;
      cv_compute(hv[j], gv[j], c, v);
      H[j] = fmaf(c, H[j], v);
    }
    o.x = f2bu(H[0]); o.y = f2bu(H[1]); o.z = f2bu(H[2]); o.w = f2bu(H[3]);
    *(ushort4*)po = o;
    ph += NN;
    po += Di;
  }
}

// ---------- launch ----------
extern "C" void kernel_launch(void* const* d_in, const int* in_sizes, int n_in,
                              void* d_out, int out_size, void* d_ws, size_t ws_size,
                              hipStream_t stream) {
  const int B = 4, S = 4096, D = 2048, Di = 3072, NN = 6144;
  const int Mr = B * S;       // 16384
  const int NCH = 32;         // chunks per sequence (chunk length 128)

  const float* x = (const float*)d_in[0];
  const float* w_hg = (const float*)d_in[1];
  const float* w_out = (const float*)d_in[2];
  float* out = (float*)d_out;

  char* wp = (char*)d_ws;
  bf16* x_bf = (bf16*)wp;  wp += (size_t)Mr * D * 2;        // 67.1 MB
  bf16* whgT = (bf16*)wp;  wp += (size_t)NN * D * 2;        // 25.2 MB
  bf16* woutT = (bf16*)wp; wp += (size_t)D * Di * 2;        // 12.6 MB
  bf16* h_bf = (bf16*)wp;  wp += (size_t)Mr * Di * 2;       // 100.7 MB
  float* P = (float*)wp;   wp += (size_t)B * NCH * Di * 4;  // 1.6 MB
  float* V = (float*)wp;   wp += (size_t)B * NCH * Di * 4;
  float* Hc = (float*)wp;  wp += (size_t)B * NCH * Di * 4;
  size_t used = (size_t)(wp - (char*)d_ws);
  bool f32hg = (used + (size_t)Mr * NN * 4) <= ws_size;  // constant across calls
  void* hgp = (void*)wp;

  // conversions / transposes
  cvt_f32_bf16<<<(int)(((long)Mr * D / 4 + 255) / 256), 256, 0, stream>>>(x, x_bf, (long)Mr * D / 4);
  transpose_f32_to_bf16<<<dim3(NN / 32, D / 32), 256, 0, stream>>>(w_hg, whgT, D, NN);
  transpose_f32_to_bf16<<<dim3(D / 32, Di / 32), 256, 0, stream>>>(w_out, woutT, Di, D);

  const int nwg1 = (NN / 256) * (Mr / 256);  // 24*64 = 1536
  const int nwg2 = (D / 256) * (Mr / 256);   // 8*64  = 512
  int scan_vthreads = B * NCH * (Di / 4);    // 98304

  if (f32hg) {
    float* hg = (float*)hgp;
    gemm256<float><<<nwg1, 512, 0, stream>>>(x_bf, whgT, hg, Mr, NN, D);
    scan_pass1<float><<<scan_vthreads / 256, 256, 0, stream>>>(hg, P, V, S, Di, NN, NCH);
    scan_pass2<<<(B * Di) / 256, 256, 0, stream>>>(P, V, Hc, Di, NCH);
    scan_pass3<float><<<scan_vthreads / 256, 256, 0, stream>>>(hg, Hc, h_bf, S, Di, NN, NCH);
  } else {
    bf16* hg = (bf16*)hgp;
    gemm256<bf16><<<nwg1, 512, 0, stream>>>(x_bf, whgT, hg, Mr, NN, D);
    scan_pass1<bf16><<<scan_vthreads / 256, 256, 0, stream>>>(hg, P, V, S, Di, NN, NCH);
    scan_pass2<<<(B * Di) / 256, 256, 0, stream>>>(P, V, Hc, Di, NCH);
    scan_pass3<bf16><<<scan_vthreads / 256, 256, 0, stream>>>(hg, Hc, h_bf, S, Di, NN, NCH);
  }

  gemm256<float><<<nwg2, 512, 0, stream>>>(h_bf, woutT, out, Mr, D, Di);
}

// Round 3
// 951.717 us; speedup vs baseline: 1.0749x; 1.0749x over previous
//
#include <hip/hip_runtime.h>
#include <hip/hip_bf16.h>
#include <stdint.h>

typedef __hip_bfloat16 bf16;
typedef __attribute__((ext_vector_type(8))) short short8;
typedef __attribute__((ext_vector_type(4))) float floatx4;
typedef __attribute__((address_space(3))) const unsigned short lu16;

// ---------- helpers ----------
__device__ __forceinline__ unsigned short f2bu(float f) {
  bf16 b = __float2bfloat16(f);
  return *reinterpret_cast<unsigned short*>(&b);
}

__device__ __forceinline__ void stf(float* p, float v) { *p = v; }
__device__ __forceinline__ void stf(bf16* p, float v) { *p = __float2bfloat16(v); }

// vectorized 4-element loads -> f32 lanes (bf16 source: 8B/lane)
__device__ __forceinline__ void ld4(const bf16* p, float* o) {
  ushort4 v = *(const ushort4*)p;
  o[0] = __bfloat162float(*(bf16*)&v.x);
  o[1] = __bfloat162float(*(bf16*)&v.y);
  o[2] = __bfloat162float(*(bf16*)&v.z);
  o[3] = __bfloat162float(*(bf16*)&v.w);
}

// async global->LDS, 16B per lane; lds base wave-uniform, HW writes base + lane*16
__device__ __forceinline__ void gl_lds16(const bf16* g, bf16* l) {
  __builtin_amdgcn_global_load_lds((const __attribute__((address_space(1))) void*)g,
                                   (__attribute__((address_space(3))) void*)l,
                                   16, 0, 0);
}

// inline-asm ds_read_b128 with compile-time byte offset
template <int OFF>
__device__ __forceinline__ short8 ldsro(lu16* p) {
  short8 r;
  asm volatile("ds_read_b128 %0, %1 offset:%2" : "=v"(r) : "v"(p), "i"(OFF));
  return r;
}

#define BAR() __builtin_amdgcn_s_barrier()
#define LGKM0() do { asm volatile("s_waitcnt lgkmcnt(0)" ::: "memory"); \
                     __builtin_amdgcn_sched_barrier(0); } while (0)
#define VMCNT(n) asm volatile("s_waitcnt vmcnt(" #n ")" ::: "memory")

// ---------- conversions ----------
__global__ void cvt_f32_bf16(const float* __restrict__ in, bf16* __restrict__ out, long n4) {
  long i = (long)blockIdx.x * blockDim.x + threadIdx.x;
  if (i >= n4) return;
  float4 v = ((const float4*)in)[i];
  ushort4 o;
  o.x = f2bu(v.x); o.y = f2bu(v.y); o.z = f2bu(v.z); o.w = f2bu(v.w);
  ((ushort4*)out)[i] = o;
}

// in: [R][Cc] f32 -> out: [Cc][R] bf16   (R, Cc multiples of 32)
__global__ void transpose_f32_to_bf16(const float* __restrict__ in, bf16* __restrict__ out,
                                      int R, int Cc) {
  __shared__ float tile[32][33];
  int tx = threadIdx.x & 31;
  int ty = threadIdx.x >> 5;  // 0..7
  int c0 = blockIdx.x * 32;
  int r0 = blockIdx.y * 32;
#pragma unroll
  for (int i = 0; i < 32; i += 8)
    tile[ty + i][tx] = in[(long)(r0 + ty + i) * Cc + c0 + tx];
  __syncthreads();
#pragma unroll
  for (int i = 0; i < 32; i += 8)
    out[(long)(c0 + ty + i) * R + r0 + tx] = __float2bfloat16(tile[tx][ty + i]);
}

// ---------- GEMM: C[M][N] = A[M][K] * BT[N][K]^T, bf16 in, OUT_T out ----------
// 256x256 tile, BK=64, 512 threads = 8 waves (2M x 4N), mfma_f32_16x16x32_bf16.
// 8-phase schedule, counted vmcnt(6) at phases 4/8, LDS XOR swizzle (16B slot
// c8 of row r at phys c8 ^ (r&7); staging pre-swizzles the global source).
// Earliest-legal staging calendar (per 4-phase KTILE on buf X reading tile t,
// other buf Y holds t+1): P1 stages A(t+1)h1 [Y], P3 stages B(t+2)h0 [X],
// P4 stages B(t+2)h1 + A(t+2)h0 [X] (buf-X A last read at P3, B at P2).
// vmcnt(6) at P4-end drains exactly through A(t+1)h1 -> 3-4 phase cover on A
// (was 2), 4-5 on B.  Requires M%256==0, N%256==0, K%128==0, gridDim.x%8==0.
template <typename OUT_T>
__global__ __launch_bounds__(512, 2) void gemm256(const bf16* __restrict__ A,
                                                  const bf16* __restrict__ BT,
                                                  OUT_T* __restrict__ C,
                                                  int M, int N, int K) {
  __shared__ __align__(16) bf16 lds[2][2][256][64];  // [buf][A/B][row][k] = 128 KiB

  const int tid = threadIdx.x;
  const int w = tid >> 6;
  const int lane = tid & 63;
  const int quad = lane >> 4;
  const int r16 = lane & 15;
  const int wm = (w >> 2) * 128;  // wave row block
  const int wn = (w & 3) * 64;    // wave col block

  // XCD-bijective swizzle (T1): gridDim.x % 8 == 0
  const int nbx = N >> 8;
  const int nwg = nbx * (M >> 8);
  const int bid = blockIdx.x;
  const int swz = (bid & 7) * (nwg >> 3) + (bid >> 3);
  const long bM = (long)(swz / nbx) * 256;
  const long bN = (long)(swz % nbx) * 256;

  // staging per-lane source coords
  const int r0 = tid >> 3;                       // 0..63 (i=1 adds 64 rows)
  const int c8 = (tid & 7) ^ (r0 & 7);
  const bf16* Ag = A + (bM + r0) * (long)K + c8 * 8;
  const bf16* Bg = BT + (bN + r0) * (long)K + c8 * 8;
  const int lslot = w * 512;                     // wave-uniform LDS elem base

  bf16* Am0 = &lds[0][0][0][0];
  bf16* Am1 = &lds[1][0][0][0];
  bf16* Bm0 = &lds[0][1][0][0];
  bf16* Bm1 = &lds[1][1][0][0];

  auto stage = [&](const bf16* g, bf16* lmat, int half, int kt) {
    const bf16* gs = g + (long)half * 128 * K + (long)kt * 64;
    bf16* ls = lmat + half * 8192 + lslot;
    gl_lds16(gs, ls);
    gl_lds16(gs + 64L * K, ls + 4096);
  };

  // fragment read bases (AS3, swizzled)
  const int lofsA = (wm + r16) * 64;
  const int lofsB = (wn + r16) * 64;
  const int c8x0 = ((0 * 4 + quad) ^ (r16 & 7)) * 8;
  const int c8x1 = ((1 * 4 + quad) ^ (r16 & 7)) * 8;
  lu16* lb = (lu16*)&lds[0][0][0][0];
  lu16* pA0k0 = lb + 0 * 32768 + 0 * 16384 + lofsA + c8x0;
  lu16* pA0k1 = lb + 0 * 32768 + 0 * 16384 + lofsA + c8x1;
  lu16* pA1k0 = lb + 1 * 32768 + 0 * 16384 + lofsA + c8x0;
  lu16* pA1k1 = lb + 1 * 32768 + 0 * 16384 + lofsA + c8x1;
  lu16* pB0k0 = lb + 0 * 32768 + 1 * 16384 + lofsB + c8x0;
  lu16* pB0k1 = lb + 0 * 32768 + 1 * 16384 + lofsB + c8x1;
  lu16* pB1k0 = lb + 1 * 32768 + 1 * 16384 + lofsB + c8x0;
  lu16* pB1k1 = lb + 1 * 32768 + 1 * 16384 + lofsB + c8x1;

  floatx4 acc[8][4];
#pragma unroll
  for (int a = 0; a < 8; a++)
#pragma unroll
    for (int b = 0; b < 4; b++) acc[a][b] = (floatx4){0.f, 0.f, 0.f, 0.f};

  short8 af[4][2], bq0[2][2], bq1[2][2];

#define READ_A(P0, P1, MG) do { \
  af[0][0] = ldsro<((MG)*4 + 0) * 2048>(P0); af[0][1] = ldsro<((MG)*4 + 0) * 2048>(P1); \
  af[1][0] = ldsro<((MG)*4 + 1) * 2048>(P0); af[1][1] = ldsro<((MG)*4 + 1) * 2048>(P1); \
  af[2][0] = ldsro<((MG)*4 + 2) * 2048>(P0); af[2][1] = ldsro<((MG)*4 + 2) * 2048>(P1); \
  af[3][0] = ldsro<((MG)*4 + 3) * 2048>(P0); af[3][1] = ldsro<((MG)*4 + 3) * 2048>(P1); \
} while (0)

#define READ_B(P0, P1, NG, BQ) do { \
  BQ[0][0] = ldsro<((NG)*2 + 0) * 2048>(P0); BQ[0][1] = ldsro<((NG)*2 + 0) * 2048>(P1); \
  BQ[1][0] = ldsro<((NG)*2 + 1) * 2048>(P0); BQ[1][1] = ldsro<((NG)*2 + 1) * 2048>(P1); \
} while (0)

#define PH_MMA(MG, NG, BQ) do { \
  __builtin_amdgcn_s_setprio(1); \
  _Pragma("unroll") \
  for (int mf = 0; mf < 4; ++mf) \
    _Pragma("unroll") \
    for (int nf = 0; nf < 2; ++nf) { \
      acc[(MG)*4 + mf][(NG)*2 + nf] = __builtin_amdgcn_mfma_f32_16x16x32_bf16( \
          af[mf][0], BQ[nf][0], acc[(MG)*4 + mf][(NG)*2 + nf], 0, 0, 0); \
      acc[(MG)*4 + mf][(NG)*2 + nf] = __builtin_amdgcn_mfma_f32_16x16x32_bf16( \
          af[mf][1], BQ[nf][1], acc[(MG)*4 + mf][(NG)*2 + nf], 0, 0, 0); \
    } \
  __builtin_amdgcn_s_setprio(0); \
} while (0)

// 4 phases for one K-tile; stage slots: S1 at P1, S3 at P3, S4a+S4b at P4
#define KTILE(PA0, PA1, PB0, PB1, S1, S3, S4a, S4b, VMX) do { \
  READ_A(PA0, PA1, 0); READ_B(PB0, PB1, 0, bq0); S1; \
  BAR(); LGKM0(); PH_MMA(0, 0, bq0); BAR(); \
  READ_B(PB0, PB1, 1, bq1); \
  BAR(); LGKM0(); PH_MMA(0, 1, bq1); BAR(); \
  READ_A(PA0, PA1, 1); S3; \
  BAR(); LGKM0(); PH_MMA(1, 1, bq1); BAR(); \
  S4a; S4b; BAR(); PH_MMA(1, 0, bq0); VMX; BAR(); \
} while (0)

  // prologue: tile0 -> buf0 (8 loads); B1h0 (2); B1h1 + A1h0 (4); drain tile0
  stage(Ag, Am0, 0, 0); stage(Ag, Am0, 1, 0);
  stage(Bg, Bm0, 0, 0); stage(Bg, Bm0, 1, 0);
  stage(Bg, Bm1, 0, 1);
  stage(Bg, Bm1, 1, 1); stage(Ag, Am1, 0, 1);
  VMCNT(6);
  BAR();

  // steady-state calendar per iteration i (tile 2i in buf0, 2i+1 in buf1):
  //  KTILE_A: P1: A(2i+1)h1 [buf1]; P3: B(2i+2)h0; P4: B(2i+2)h1 + A(2i+2)h0 [buf0]
  //           vmcnt(6) drains through A(2i+1)h1  -> tile 2i+1 complete
  //  KTILE_B: P5: A(2i+2)h1 [buf0]; P7: B(2i+3)h0; P8: B(2i+3)h1 + A(2i+3)h0 [buf1]
  //           vmcnt(6) drains through A(2i+2)h1  -> tile 2i+2 complete
  const int NI = K >> 7;
  for (int i = 0; i < NI - 1; ++i) {
    const int k1 = 2 * i + 1, k2 = 2 * i + 2, k3 = 2 * i + 3;
    KTILE(pA0k0, pA0k1, pB0k0, pB0k1,
          stage(Ag, Am1, 1, k1),
          stage(Bg, Bm0, 0, k2),
          stage(Bg, Bm0, 1, k2), stage(Ag, Am0, 0, k2), VMCNT(6));
    KTILE(pA1k0, pA1k1, pB1k0, pB1k1,
          stage(Ag, Am0, 1, k2),
          stage(Bg, Bm1, 0, k3),
          stage(Bg, Bm1, 1, k3), stage(Ag, Am1, 0, k3), VMCNT(6));
  }
  {
    const int kl = 2 * NI - 1;  // last odd tile: only its A h1 remains to stage
    KTILE(pA0k0, pA0k1, pB0k0, pB0k1,
          stage(Ag, Am1, 1, kl),
          (void)0, (void)0, (void)0, VMCNT(0));
    KTILE(pA1k0, pA1k1, pB1k0, pB1k1,
          (void)0, (void)0, (void)0, (void)0, (void)0);
  }

#undef KTILE
#undef PH_MMA
#undef READ_B
#undef READ_A

  // C/D layout: col = lane&15, row = quad*4 + reg  (plain cached stores)
#pragma unroll
  for (int mf = 0; mf < 8; ++mf) {
#pragma unroll
    for (int i2 = 0; i2 < 4; ++i2) {
      long row = bM + wm + mf * 16 + quad * 4 + i2;
      OUT_T* crow = C + row * (long)N + bN + wn + r16;
#pragma unroll
      for (int nf = 0; nf < 4; ++nf) stf(&crow[nf * 16], acc[mf][nf][i2]);
    }
  }
}

// ---------- scan ----------
// c = sigmoid(-gate), v = sigmoid(gate) * g(hidden); g(x) = x>=0 ? x+0.5 : sigmoid(x)
__device__ __forceinline__ void cv_compute(float hval, float gval, float& c, float& v) {
  float eg = __expf(gval);
  c = 1.f / (1.f + eg);
  float z = 1.f - c;
  float gx = (hval >= 0.f) ? (hval + 0.5f) : (1.f / (1.f + __expf(-hval)));
  v = z * gx;
}

// pass1: per (b, chunk, e-quad): P = prod c, V = local recurrence from 0 (4 elems/thread)
__global__ void scan_pass1(const bf16* __restrict__ hg, float* __restrict__ P,
                           float* __restrict__ V, int S, int Di, int NN, int nch) {
  int tid = blockIdx.x * blockDim.x + threadIdx.x;  // over B*nch*(Di/4)
  int De = Di >> 2;
  int e = (tid % De) * 4;
  int rest = tid / De;
  int ch = rest % nch;
  int b = rest / nch;
  int CH = S / nch;
  const bf16* ph = hg + ((long)(b * S + ch * CH)) * NN + e;
  float Pv[4] = {1.f, 1.f, 1.f, 1.f}, Vv[4] = {0.f, 0.f, 0.f, 0.f};
  for (int t = 0; t < CH; t++) {
    float hv[4], gv[4];
    ld4(ph, hv);
    ld4(ph + Di, gv);
#pragma unroll
    for (int j = 0; j < 4; j++) {
      float c, v;
      cv_compute(hv[j], gv[j], c, v);
      Pv[j] *= c;
      Vv[j] = fmaf(c, Vv[j], v);
    }
    ph += NN;
  }
  long base = ((long)(b * nch + ch)) * Di + e;
  *(float4*)&P[base] = make_float4(Pv[0], Pv[1], Pv[2], Pv[3]);
  *(float4*)&V[base] = make_float4(Vv[0], Vv[1], Vv[2], Vv[3]);
}

// pass2: scan the chunk summaries, store carry-in per chunk
__global__ void scan_pass2(const float* __restrict__ P, const float* __restrict__ V,
                           float* __restrict__ Hc, int Di, int nch) {
  int tid = blockIdx.x * blockDim.x + threadIdx.x;  // b*Di + e
  int e = tid % Di;
  int b = tid / Di;
  float H = 0.f;
  for (int j = 0; j < nch; j++) {
    long idx = ((long)(b * nch + j)) * Di + e;
    Hc[idx] = H;
    H = fmaf(P[idx], H, V[idx]);
  }
}

// pass3: replay chunk with carry, write h (bf16), 4 elems/thread
__global__ void scan_pass3(const bf16* __restrict__ hg, const float* __restrict__ Hc,
                           bf16* __restrict__ h, int S, int Di, int NN, int nch) {
  int tid = blockIdx.x * blockDim.x + threadIdx.x;  // over B*nch*(Di/4)
  int De = Di >> 2;
  int e = (tid % De) * 4;
  int rest = tid / De;
  int ch = rest % nch;
  int b = rest / nch;
  int CH = S / nch;
  const bf16* ph = hg + ((long)(b * S + ch * CH)) * NN + e;
  bf16* po = h + ((long)(b * S + ch * CH)) * Di + e;
  long base = ((long)(b * nch + ch)) * Di + e;
  float4 hc = *(const float4*)&Hc[base];
  float H[4] = {hc.x, hc.y, hc.z, hc.w};
  for (int t = 0; t < CH; t++) {
    float hv[4], gv[4];
    ld4(ph, hv);
    ld4(ph + Di, gv);
    ushort4 o;
#pragma unroll
    for (int j = 0; j < 4; j++) {
      float c, v;
      cv_compute(hv[j], gv[j], c, v);
      H[j] = fmaf(c, H[j], v);
    }
    o.x = f2bu(H[0]); o.y = f2bu(H[1]); o.z = f2bu(H[2]); o.w = f2bu(H[3]);
    *(ushort4*)po = o;
    ph += NN;
    po += Di;
  }
}

// ---------- launch ----------
extern "C" void kernel_launch(void* const* d_in, const int* in_sizes, int n_in,
                              void* d_out, int out_size, void* d_ws, size_t ws_size,
                              hipStream_t stream) {
  const int B = 4, S = 4096, D = 2048, Di = 3072, NN = 6144;
  const int Mr = B * S;       // 16384
  const int NCH = 64;         // chunks per sequence (chunk length 64)

  const float* x = (const float*)d_in[0];
  const float* w_hg = (const float*)d_in[1];
  const float* w_out = (const float*)d_in[2];
  float* out = (float*)d_out;

  char* wp = (char*)d_ws;
  bf16* x_bf = (bf16*)wp;  wp += (size_t)Mr * D * 2;        // 67.1 MB
  bf16* whgT = (bf16*)wp;  wp += (size_t)NN * D * 2;        // 25.2 MB
  bf16* woutT = (bf16*)wp; wp += (size_t)D * Di * 2;        // 12.6 MB
  bf16* h_bf = (bf16*)wp;  wp += (size_t)Mr * Di * 2;       // 100.7 MB
  bf16* hg = (bf16*)wp;    wp += (size_t)Mr * NN * 2;       // 201.3 MB

  // P/V/Hc alias the front of x_bf: x_bf is dead after gemm1 reads it, and
  // is fully rewritten by cvt before the next iteration's gemm1. P/V/Hc are
  // written by pass1/2 (after gemm1) and dead after pass3 -- no overlap.
  float* P = (float*)x_bf;                                  // 3.15 MB
  float* V = P + (size_t)B * NCH * Di;                      // 3.15 MB
  float* Hc = V + (size_t)B * NCH * Di;                     // 3.15 MB

  // conversions / transposes
  cvt_f32_bf16<<<(int)(((long)Mr * D / 4 + 255) / 256), 256, 0, stream>>>(x, x_bf, (long)Mr * D / 4);
  transpose_f32_to_bf16<<<dim3(NN / 32, D / 32), 256, 0, stream>>>(w_hg, whgT, D, NN);
  transpose_f32_to_bf16<<<dim3(D / 32, Di / 32), 256, 0, stream>>>(w_out, woutT, Di, D);

  const int nwg1 = (NN / 256) * (Mr / 256);  // 24*64 = 1536
  const int nwg2 = (D / 256) * (Mr / 256);   // 8*64  = 512
  int scan_vthreads = B * NCH * (Di / 4);    // 196608

  gemm256<bf16><<<nwg1, 512, 0, stream>>>(x_bf, whgT, hg, Mr, NN, D);
  scan_pass1<<<scan_vthreads / 256, 256, 0, stream>>>(hg, P, V, S, Di, NN, NCH);
  scan_pass2<<<(B * Di) / 256, 256, 0, stream>>>(P, V, Hc, Di, NCH);
  scan_pass3<<<scan_vthreads / 256, 256, 0, stream>>>(hg, Hc, h_bf, S, Di, NN, NCH);

  gemm256<float><<<nwg2, 512, 0, stream>>>(h_bf, woutT, out, Mr, D, Di);
}

// Round 4
// 936.176 us; speedup vs baseline: 1.0927x; 1.0166x over previous
//
#include <hip/hip_runtime.h>
#include <hip/hip_bf16.h>
#include <stdint.h>

typedef __hip_bfloat16 bf16;
typedef __attribute__((ext_vector_type(8))) short short8;
typedef __attribute__((ext_vector_type(4))) float floatx4;
typedef __attribute__((address_space(3))) const unsigned short lu16;

// ---------- helpers ----------
__device__ __forceinline__ unsigned short f2bu(float f) {
  bf16 b = __float2bfloat16(f);
  return *reinterpret_cast<unsigned short*>(&b);
}

__device__ __forceinline__ void stf(float* p, float v) { *p = v; }
__device__ __forceinline__ void stf(bf16* p, float v) { *p = __float2bfloat16(v); }

// vectorized 4-element loads -> f32 lanes (bf16 source: 8B/lane)
__device__ __forceinline__ void ld4(const bf16* p, float* o) {
  ushort4 v = *(const ushort4*)p;
  o[0] = __bfloat162float(*(bf16*)&v.x);
  o[1] = __bfloat162float(*(bf16*)&v.y);
  o[2] = __bfloat162float(*(bf16*)&v.z);
  o[3] = __bfloat162float(*(bf16*)&v.w);
}

// async global->LDS, 16B per lane; lds base wave-uniform, HW writes base + lane*16
__device__ __forceinline__ void gl_lds16(const bf16* g, bf16* l) {
  __builtin_amdgcn_global_load_lds((const __attribute__((address_space(1))) void*)g,
                                   (__attribute__((address_space(3))) void*)l,
                                   16, 0, 0);
}

// inline-asm ds_read_b128 with compile-time byte offset
template <int OFF>
__device__ __forceinline__ short8 ldsro(lu16* p) {
  short8 r;
  asm volatile("ds_read_b128 %0, %1 offset:%2" : "=v"(r) : "v"(p), "i"(OFF));
  return r;
}

#define BAR() __builtin_amdgcn_s_barrier()
#define WAITLG(n) do { asm volatile("s_waitcnt lgkmcnt(" #n ")" ::: "memory"); \
                       __builtin_amdgcn_sched_barrier(0); } while (0)
#define VMCNT(n) asm volatile("s_waitcnt vmcnt(" #n ")" ::: "memory")

// ---------- conversions ----------
__global__ void cvt_f32_bf16(const float* __restrict__ in, bf16* __restrict__ out, long n4) {
  long i = (long)blockIdx.x * blockDim.x + threadIdx.x;
  if (i >= n4) return;
  float4 v = ((const float4*)in)[i];
  ushort4 o;
  o.x = f2bu(v.x); o.y = f2bu(v.y); o.z = f2bu(v.z); o.w = f2bu(v.w);
  ((ushort4*)out)[i] = o;
}

// in: [R][Cc] f32 -> out: [Cc][R] bf16   (R, Cc multiples of 32)
__global__ void transpose_f32_to_bf16(const float* __restrict__ in, bf16* __restrict__ out,
                                      int R, int Cc) {
  __shared__ float tile[32][33];
  int tx = threadIdx.x & 31;
  int ty = threadIdx.x >> 5;  // 0..7
  int c0 = blockIdx.x * 32;
  int r0 = blockIdx.y * 32;
#pragma unroll
  for (int i = 0; i < 32; i += 8)
    tile[ty + i][tx] = in[(long)(r0 + ty + i) * Cc + c0 + tx];
  __syncthreads();
#pragma unroll
  for (int i = 0; i < 32; i += 8)
    out[(long)(c0 + ty + i) * R + r0 + tx] = __float2bfloat16(tile[tx][ty + i]);
}

// ---------- GEMM: C[M][N] = A[M][K] * BT[N][K]^T, bf16 in, OUT_T out ----------
// 256x256 tile, BK=64, 512 threads = 8 waves (2M x 4N), mfma_f32_16x16x32_bf16.
// 8-phase schedule with ONE barrier per phase (phase-end only): each wave's
// counted lgkm waits complete its ds_reads before its MFMA and before the
// phase-end barrier, so stage-overwrites (>=1 barrier later per the round-1
// calendar) stay safe while fast waves' MFMAs overlap slow waves' reads.
// bq1 issued at P1 (drains during P1 MFMA); staggered per-mf-group lgkm waits
// expose only the first few reads' latency.  vmcnt(4) at P4/P8 publishes the
// next tile.  LDS XOR swizzle: 16B slot c8 of row r at phys c8 ^ (r&7).
// Requires M%256==0, N%256==0, K%128==0, gridDim.x%8==0.
template <typename OUT_T>
__global__ __launch_bounds__(512, 2) void gemm256(const bf16* __restrict__ A,
                                                  const bf16* __restrict__ BT,
                                                  OUT_T* __restrict__ C,
                                                  int M, int N, int K) {
  __shared__ __align__(16) bf16 lds[2][2][256][64];  // [buf][A/B][row][k] = 128 KiB

  const int tid = threadIdx.x;
  const int w = tid >> 6;
  const int lane = tid & 63;
  const int quad = lane >> 4;
  const int r16 = lane & 15;
  const int wm = (w >> 2) * 128;  // wave row block
  const int wn = (w & 3) * 64;    // wave col block

  // XCD-bijective swizzle (T1): gridDim.x % 8 == 0
  const int nbx = N >> 8;
  const int nwg = nbx * (M >> 8);
  const int bid = blockIdx.x;
  const int swz = (bid & 7) * (nwg >> 3) + (bid >> 3);
  const long bM = (long)(swz / nbx) * 256;
  const long bN = (long)(swz % nbx) * 256;

  // staging per-lane source coords
  const int r0 = tid >> 3;                       // 0..63 (i=1 adds 64 rows)
  const int c8 = (tid & 7) ^ (r0 & 7);
  const bf16* Ag = A + (bM + r0) * (long)K + c8 * 8;
  const bf16* Bg = BT + (bN + r0) * (long)K + c8 * 8;
  const int lslot = w * 512;                     // wave-uniform LDS elem base

  bf16* Am0 = &lds[0][0][0][0];
  bf16* Am1 = &lds[1][0][0][0];
  bf16* Bm0 = &lds[0][1][0][0];
  bf16* Bm1 = &lds[1][1][0][0];

  auto stage = [&](const bf16* g, bf16* lmat, int half, int kt) {
    const bf16* gs = g + (long)half * 128 * K + (long)kt * 64;
    bf16* ls = lmat + half * 8192 + lslot;
    gl_lds16(gs, ls);
    gl_lds16(gs + 64L * K, ls + 4096);
  };

  // fragment read bases (AS3, swizzled)
  const int lofsA = (wm + r16) * 64;
  const int lofsB = (wn + r16) * 64;
  const int c8x0 = ((0 * 4 + quad) ^ (r16 & 7)) * 8;
  const int c8x1 = ((1 * 4 + quad) ^ (r16 & 7)) * 8;
  lu16* lb = (lu16*)&lds[0][0][0][0];
  lu16* pA0k0 = lb + 0 * 32768 + 0 * 16384 + lofsA + c8x0;
  lu16* pA0k1 = lb + 0 * 32768 + 0 * 16384 + lofsA + c8x1;
  lu16* pA1k0 = lb + 1 * 32768 + 0 * 16384 + lofsA + c8x0;
  lu16* pA1k1 = lb + 1 * 32768 + 0 * 16384 + lofsA + c8x1;
  lu16* pB0k0 = lb + 0 * 32768 + 1 * 16384 + lofsB + c8x0;
  lu16* pB0k1 = lb + 0 * 32768 + 1 * 16384 + lofsB + c8x1;
  lu16* pB1k0 = lb + 1 * 32768 + 1 * 16384 + lofsB + c8x0;
  lu16* pB1k1 = lb + 1 * 32768 + 1 * 16384 + lofsB + c8x1;

  floatx4 acc[8][4];
#pragma unroll
  for (int a = 0; a < 8; a++)
#pragma unroll
    for (int b = 0; b < 4; b++) acc[a][b] = (floatx4){0.f, 0.f, 0.f, 0.f};

  short8 af[4][2], bq0[2][2], bq1[2][2];

// 4 MFMAs: af[MF] (2 k-chunks) x BQ[0..1] -> acc[AR][NB], acc[AR][NB+1]
#define MMAG(AR, MF, NB, BQ) do { \
  acc[AR][NB]     = __builtin_amdgcn_mfma_f32_16x16x32_bf16(af[MF][0], BQ[0][0], acc[AR][NB], 0, 0, 0); \
  acc[AR][NB]     = __builtin_amdgcn_mfma_f32_16x16x32_bf16(af[MF][1], BQ[0][1], acc[AR][NB], 0, 0, 0); \
  acc[AR][NB + 1] = __builtin_amdgcn_mfma_f32_16x16x32_bf16(af[MF][0], BQ[1][0], acc[AR][NB + 1], 0, 0, 0); \
  acc[AR][NB + 1] = __builtin_amdgcn_mfma_f32_16x16x32_bf16(af[MF][1], BQ[1][1], acc[AR][NB + 1], 0, 0, 0); \
} while (0)

// P1 issue order: af0(#1-2), bq0(#3-6), af1(#7-8), af2(#9-10), af3(#11-12), bq1(#13-16)
#define ISSUE_P1(PA0, PA1, PB0, PB1) do { \
  af[0][0] = ldsro<0>(PA0);     af[0][1] = ldsro<0>(PA1); \
  bq0[0][0] = ldsro<0>(PB0);    bq0[0][1] = ldsro<0>(PB1); \
  bq0[1][0] = ldsro<2048>(PB0); bq0[1][1] = ldsro<2048>(PB1); \
  af[1][0] = ldsro<2048>(PA0);  af[1][1] = ldsro<2048>(PA1); \
  af[2][0] = ldsro<4096>(PA0);  af[2][1] = ldsro<4096>(PA1); \
  af[3][0] = ldsro<6144>(PA0);  af[3][1] = ldsro<6144>(PA1); \
  bq1[0][0] = ldsro<4096>(PB0); bq1[0][1] = ldsro<4096>(PB1); \
  bq1[1][0] = ldsro<6144>(PB0); bq1[1][1] = ldsro<6144>(PB1); \
} while (0)

// P3 issue: af MG1 pairs (#1-2 .. #7-8), offsets (4+mf)*2048
#define ISSUE_P3(PA0, PA1) do { \
  af[0][0] = ldsro<8192>(PA0);  af[0][1] = ldsro<8192>(PA1); \
  af[1][0] = ldsro<10240>(PA0); af[1][1] = ldsro<10240>(PA1); \
  af[2][0] = ldsro<12288>(PA0); af[2][1] = ldsro<12288>(PA1); \
  af[3][0] = ldsro<14336>(PA0); af[3][1] = ldsro<14336>(PA1); \
} while (0)

// one K-tile (4 phases, 1 barrier each); S1..S4 staging stmts; VMX at P4
#define KTILE(PA0, PA1, PB0, PB1, S1, S2, S3, S4, VMX) do { \
  /* P1: MFMA(MG0,NG0) */ \
  ISSUE_P1(PA0, PA1, PB0, PB1); S1; \
  __builtin_amdgcn_s_setprio(1); \
  WAITLG(10); MMAG(0, 0, 0, bq0); \
  WAITLG(8);  MMAG(1, 1, 0, bq0); \
  WAITLG(6);  MMAG(2, 2, 0, bq0); \
  WAITLG(4);  MMAG(3, 3, 0, bq0); \
  __builtin_amdgcn_s_setprio(0); BAR(); \
  /* P2: MFMA(MG0,NG1) -- bq1 drained during P1 MFMA */ \
  S2; WAITLG(0); \
  __builtin_amdgcn_s_setprio(1); \
  MMAG(0, 0, 2, bq1); MMAG(1, 1, 2, bq1); MMAG(2, 2, 2, bq1); MMAG(3, 3, 2, bq1); \
  __builtin_amdgcn_s_setprio(0); BAR(); \
  /* P3: MFMA(MG1,NG1) */ \
  ISSUE_P3(PA0, PA1); S3; \
  __builtin_amdgcn_s_setprio(1); \
  WAITLG(6); MMAG(4, 0, 2, bq1); \
  WAITLG(4); MMAG(5, 1, 2, bq1); \
  WAITLG(2); MMAG(6, 2, 2, bq1); \
  WAITLG(0); MMAG(7, 3, 2, bq1); \
  __builtin_amdgcn_s_setprio(0); BAR(); \
  /* P4: MFMA(MG1,NG0) -- all frags in regs */ \
  S4; \
  __builtin_amdgcn_s_setprio(1); \
  MMAG(4, 0, 0, bq0); MMAG(5, 1, 0, bq0); MMAG(6, 2, 0, bq0); MMAG(7, 3, 0, bq0); \
  __builtin_amdgcn_s_setprio(0); \
  VMX; BAR(); \
} while (0)

  // prologue: tile0 -> buf0 (8 loads), tile1 B -> buf1 (4 loads); drain tile0
  stage(Ag, Am0, 0, 0); stage(Ag, Am0, 1, 0);
  stage(Bg, Bm0, 0, 0); stage(Bg, Bm0, 1, 0);
  stage(Bg, Bm1, 0, 1); stage(Bg, Bm1, 1, 1);
  VMCNT(4);
  BAR();

  // staging calendar per iteration i (tiles 2i in buf0, 2i+1 in buf1):
  //  P1/P2: A halves of tile 2i+1 -> buf1; P3/P4: B halves of tile 2i+2 -> buf0
  //  P5/P6: A halves of tile 2i+2 -> buf0; P7/P8: B halves of tile 2i+3 -> buf1
  //  vmcnt(4) at P4 drains through A(2i+1) (tile 2i+1 complete before P5);
  //  vmcnt(4) at P8 drains through A(2i+2) (tile 2i+2 complete before next P1).
  const int NI = K >> 7;
  for (int i = 0; i < NI - 1; ++i) {
    const int k1 = 2 * i + 1, k2 = 2 * i + 2, k3 = 2 * i + 3;
    KTILE(pA0k0, pA0k1, pB0k0, pB0k1,
          stage(Ag, Am1, 0, k1), stage(Ag, Am1, 1, k1),
          stage(Bg, Bm0, 0, k2), stage(Bg, Bm0, 1, k2), VMCNT(4));
    KTILE(pA1k0, pA1k1, pB1k0, pB1k1,
          stage(Ag, Am0, 0, k2), stage(Ag, Am0, 1, k2),
          stage(Bg, Bm1, 0, k3), stage(Bg, Bm1, 1, k3), VMCNT(4));
  }
  {
    const int kl = 2 * NI - 1;  // last odd tile: only its A halves remain to stage
    KTILE(pA0k0, pA0k1, pB0k0, pB0k1,
          stage(Ag, Am1, 0, kl), stage(Ag, Am1, 1, kl),
          (void)0, (void)0, VMCNT(0));
    KTILE(pA1k0, pA1k1, pB1k0, pB1k1,
          (void)0, (void)0, (void)0, (void)0, (void)0);
  }

#undef KTILE
#undef ISSUE_P3
#undef ISSUE_P1
#undef MMAG

  // C/D layout: col = lane&15, row = quad*4 + reg
#pragma unroll
  for (int mf = 0; mf < 8; ++mf) {
#pragma unroll
    for (int i2 = 0; i2 < 4; ++i2) {
      long row = bM + wm + mf * 16 + quad * 4 + i2;
      OUT_T* crow = C + row * (long)N + bN + wn + r16;
#pragma unroll
      for (int nf = 0; nf < 4; ++nf) stf(&crow[nf * 16], acc[mf][nf][i2]);
    }
  }
}

// ---------- scan ----------
// c = sigmoid(-gate), v = sigmoid(gate) * g(hidden); g(x) = x>=0 ? x+0.5 : sigmoid(x)
__device__ __forceinline__ void cv_compute(float hval, float gval, float& c, float& v) {
  float eg = __expf(gval);
  c = 1.f / (1.f + eg);
  float z = 1.f - c;
  float gx = (hval >= 0.f) ? (hval + 0.5f) : (1.f / (1.f + __expf(-hval)));
  v = z * gx;
}

// pass1: per (b, chunk, e-quad): P = prod c, V = local recurrence from 0 (4 elems/thread)
__global__ void scan_pass1(const bf16* __restrict__ hg, float* __restrict__ P,
                           float* __restrict__ V, int S, int Di, int NN, int nch) {
  int tid = blockIdx.x * blockDim.x + threadIdx.x;  // over B*nch*(Di/4)
  int De = Di >> 2;
  int e = (tid % De) * 4;
  int rest = tid / De;
  int ch = rest % nch;
  int b = rest / nch;
  int CH = S / nch;
  const bf16* ph = hg + ((long)(b * S + ch * CH)) * NN + e;
  float Pv[4] = {1.f, 1.f, 1.f, 1.f}, Vv[4] = {0.f, 0.f, 0.f, 0.f};
  for (int t = 0; t < CH; t++) {
    float hv[4], gv[4];
    ld4(ph, hv);
    ld4(ph + Di, gv);
#pragma unroll
    for (int j = 0; j < 4; j++) {
      float c, v;
      cv_compute(hv[j], gv[j], c, v);
      Pv[j] *= c;
      Vv[j] = fmaf(c, Vv[j], v);
    }
    ph += NN;
  }
  long base = ((long)(b * nch + ch)) * Di + e;
  *(float4*)&P[base] = make_float4(Pv[0], Pv[1], Pv[2], Pv[3]);
  *(float4*)&V[base] = make_float4(Vv[0], Vv[1], Vv[2], Vv[3]);
}

// pass2: scan the chunk summaries, store carry-in per chunk
__global__ void scan_pass2(const float* __restrict__ P, const float* __restrict__ V,
                           float* __restrict__ Hc, int Di, int nch) {
  int tid = blockIdx.x * blockDim.x + threadIdx.x;  // b*Di + e
  int e = tid % Di;
  int b = tid / Di;
  float H = 0.f;
  for (int j = 0; j < nch; j++) {
    long idx = ((long)(b * nch + j)) * Di + e;
    Hc[idx] = H;
    H = fmaf(P[idx], H, V[idx]);
  }
}

// pass3: replay chunk with carry, write h (bf16), 4 elems/thread
__global__ void scan_pass3(const bf16* __restrict__ hg, const float* __restrict__ Hc,
                           bf16* __restrict__ h, int S, int Di, int NN, int nch) {
  int tid = blockIdx.x * blockDim.x + threadIdx.x;  // over B*nch*(Di/4)
  int De = Di >> 2;
  int e = (tid % De) * 4;
  int rest = tid / De;
  int ch = rest % nch;
  int b = rest / nch;
  int CH = S / nch;
  const bf16* ph = hg + ((long)(b * S + ch * CH)) * NN + e;
  bf16* po = h + ((long)(b * S + ch * CH)) * Di + e;
  long base = ((long)(b * nch + ch)) * Di + e;
  float4 hc = *(const float4*)&Hc[base];
  float H[4] = {hc.x, hc.y, hc.z, hc.w};
  for (int t = 0; t < CH; t++) {
    float hv[4], gv[4];
    ld4(ph, hv);
    ld4(ph + Di, gv);
    ushort4 o;
#pragma unroll
    for (int j = 0; j < 4; j++) {
      float c, v;
      cv_compute(hv[j], gv[j], c, v);
      H[j] = fmaf(c, H[j], v);
    }
    o.x = f2bu(H[0]); o.y = f2bu(H[1]); o.z = f2bu(H[2]); o.w = f2bu(H[3]);
    *(ushort4*)po = o;
    ph += NN;
    po += Di;
  }
}

// ---------- launch ----------
extern "C" void kernel_launch(void* const* d_in, const int* in_sizes, int n_in,
                              void* d_out, int out_size, void* d_ws, size_t ws_size,
                              hipStream_t stream) {
  const int B = 4, S = 4096, D = 2048, Di = 3072, NN = 6144;
  const int Mr = B * S;       // 16384
  const int NCH = 64;         // chunks per sequence (chunk length 64)

  const float* x = (const float*)d_in[0];
  const float* w_hg = (const float*)d_in[1];
  const float* w_out = (const float*)d_in[2];
  float* out = (float*)d_out;

  char* wp = (char*)d_ws;
  bf16* x_bf = (bf16*)wp;  wp += (size_t)Mr * D * 2;        // 67.1 MB
  bf16* whgT = (bf16*)wp;  wp += (size_t)NN * D * 2;        // 25.2 MB
  bf16* woutT = (bf16*)wp; wp += (size_t)D * Di * 2;        // 12.6 MB
  bf16* h_bf = (bf16*)wp;  wp += (size_t)Mr * Di * 2;       // 100.7 MB
  bf16* hg = (bf16*)wp;    wp += (size_t)Mr * NN * 2;       // 201.3 MB

  // P/V/Hc alias the front of x_bf: x_bf is dead after gemm1 reads it, and
  // is fully rewritten by cvt before the next iteration's gemm1. P/V/Hc are
  // written by pass1/2 (after gemm1) and dead after pass3 -- no overlap.
  float* P = (float*)x_bf;                                  // 3.15 MB
  float* V = P + (size_t)B * NCH * Di;                      // 3.15 MB
  float* Hc = V + (size_t)B * NCH * Di;                     // 3.15 MB

  // conversions / transposes
  cvt_f32_bf16<<<(int)(((long)Mr * D / 4 + 255) / 256), 256, 0, stream>>>(x, x_bf, (long)Mr * D / 4);
  transpose_f32_to_bf16<<<dim3(NN / 32, D / 32), 256, 0, stream>>>(w_hg, whgT, D, NN);
  transpose_f32_to_bf16<<<dim3(D / 32, Di / 32), 256, 0, stream>>>(w_out, woutT, Di, D);

  const int nwg1 = (NN / 256) * (Mr / 256);  // 24*64 = 1536
  const int nwg2 = (D / 256) * (Mr / 256);   // 8*64  = 512
  int scan_vthreads = B * NCH * (Di / 4);    // 196608

  gemm256<bf16><<<nwg1, 512, 0, stream>>>(x_bf, whgT, hg, Mr, NN, D);
  scan_pass1<<<scan_vthreads / 256, 256, 0, stream>>>(hg, P, V, S, Di, NN, NCH);
  scan_pass2<<<(B * Di) / 256, 256, 0, stream>>>(P, V, Hc, Di, NCH);
  scan_pass3<<<scan_vthreads / 256, 256, 0, stream>>>(hg, Hc, h_bf, S, Di, NN, NCH);

  gemm256<float><<<nwg2, 512, 0, stream>>>(h_bf, woutT, out, Mr, D, Di);
}

// Round 5
// 930.318 us; speedup vs baseline: 1.0996x; 1.0063x over previous
//
#include <hip/hip_runtime.h>
#include <hip/hip_bf16.h>
#include <stdint.h>

typedef __hip_bfloat16 bf16;
typedef __attribute__((ext_vector_type(8))) short short8;
typedef __attribute__((ext_vector_type(4))) float floatx4;
typedef __attribute__((address_space(3))) const unsigned short lu16;

// ---------- helpers ----------
__device__ __forceinline__ unsigned short f2bu(float f) {
  bf16 b = __float2bfloat16(f);
  return *reinterpret_cast<unsigned short*>(&b);
}

__device__ __forceinline__ void stf(float* p, float v) { *p = v; }
__device__ __forceinline__ void stf(bf16* p, float v) { *p = __float2bfloat16(v); }

// vectorized 4-element loads -> f32 lanes (bf16 source: 8B/lane)
__device__ __forceinline__ void ld4(const bf16* p, float* o) {
  ushort4 v = *(const ushort4*)p;
  o[0] = __bfloat162float(*(bf16*)&v.x);
  o[1] = __bfloat162float(*(bf16*)&v.y);
  o[2] = __bfloat162float(*(bf16*)&v.z);
  o[3] = __bfloat162float(*(bf16*)&v.w);
}

// async global->LDS, 16B per lane; lds base wave-uniform, HW writes base + lane*16
__device__ __forceinline__ void gl_lds16(const bf16* g, bf16* l) {
  __builtin_amdgcn_global_load_lds((const __attribute__((address_space(1))) void*)g,
                                   (__attribute__((address_space(3))) void*)l,
                                   16, 0, 0);
}

// inline-asm ds_read_b128 with compile-time byte offset
template <int OFF>
__device__ __forceinline__ short8 ldsro(lu16* p) {
  short8 r;
  asm volatile("ds_read_b128 %0, %1 offset:%2" : "=v"(r) : "v"(p), "i"(OFF));
  return r;
}

#define BAR() __builtin_amdgcn_s_barrier()
#define WAITLG(n) do { asm volatile("s_waitcnt lgkmcnt(" #n ")" ::: "memory"); \
                       __builtin_amdgcn_sched_barrier(0); } while (0)
#define VMCNT(n) asm volatile("s_waitcnt vmcnt(" #n ")" ::: "memory")

// ---------- conversions ----------
__global__ void cvt_f32_bf16(const float* __restrict__ in, bf16* __restrict__ out, long n4) {
  long i = (long)blockIdx.x * blockDim.x + threadIdx.x;
  if (i >= n4) return;
  float4 v = ((const float4*)in)[i];
  ushort4 o;
  o.x = f2bu(v.x); o.y = f2bu(v.y); o.z = f2bu(v.z); o.w = f2bu(v.w);
  ((ushort4*)out)[i] = o;
}

// in: [R][Cc] f32 -> out: [Cc][R] bf16   (R, Cc multiples of 32)
__global__ void transpose_f32_to_bf16(const float* __restrict__ in, bf16* __restrict__ out,
                                      int R, int Cc) {
  __shared__ float tile[32][33];
  int tx = threadIdx.x & 31;
  int ty = threadIdx.x >> 5;  // 0..7
  int c0 = blockIdx.x * 32;
  int r0 = blockIdx.y * 32;
#pragma unroll
  for (int i = 0; i < 32; i += 8)
    tile[ty + i][tx] = in[(long)(r0 + ty + i) * Cc + c0 + tx];
  __syncthreads();
#pragma unroll
  for (int i = 0; i < 32; i += 8)
    out[(long)(c0 + ty + i) * R + r0 + tx] = __float2bfloat16(tile[tx][ty + i]);
}

// ---------- GEMM: C[M][N] = A[M][K] * BT[N][K]^T, bf16 in, OUT_T out ----------
// 256x256 tile, BK=64, 512 threads = 8 waves (2M x 4N), mfma_f32_16x16x32_bf16.
// TWO phases per K-tile (was 4): Phase A = all MG0 A-frags + both B quads (16
// ds_reads, the same live register set as before) + 32 MFMA under a staggered
// lgkm wait ladder; Phase B = MG1 A-frags (8 reads) + 32 MFMA.  One barrier
// per phase; every wave reaches lgkmcnt(0) before its barrier, so each staged
// region stays >=1 barrier after its last reader:
//   A-region of buf Y (tile t+1) staged in phA(t); last read phB(t-1).
//   B-region of buf X (tile t+2) staged in phB(t); last read phA(t).
// vmcnt(4) at phB end publishes: drains {B(t+1), A(t+1)}, leaves B(t+2).
// LDS XOR swizzle: 16B slot c8 of row r at phys c8 ^ (r&7); staging
// pre-swizzles the global source.  M%256==0, N%256==0, K%128==0, grid%8==0.
template <typename OUT_T>
__global__ __launch_bounds__(512, 2) void gemm256(const bf16* __restrict__ A,
                                                  const bf16* __restrict__ BT,
                                                  OUT_T* __restrict__ C,
                                                  int M, int N, int K) {
  __shared__ __align__(16) bf16 lds[2][2][256][64];  // [buf][A/B][row][k] = 128 KiB

  const int tid = threadIdx.x;
  const int w = tid >> 6;
  const int lane = tid & 63;
  const int quad = lane >> 4;
  const int r16 = lane & 15;
  const int wm = (w >> 2) * 128;  // wave row block
  const int wn = (w & 3) * 64;    // wave col block

  // XCD-bijective swizzle (T1): gridDim.x % 8 == 0
  const int nbx = N >> 8;
  const int nwg = nbx * (M >> 8);
  const int bid = blockIdx.x;
  const int swz = (bid & 7) * (nwg >> 3) + (bid >> 3);
  const long bM = (long)(swz / nbx) * 256;
  const long bN = (long)(swz % nbx) * 256;

  // staging per-lane source coords
  const int r0 = tid >> 3;                       // 0..63 (i=1 adds 64 rows)
  const int c8 = (tid & 7) ^ (r0 & 7);
  const bf16* Ag = A + (bM + r0) * (long)K + c8 * 8;
  const bf16* Bg = BT + (bN + r0) * (long)K + c8 * 8;
  const int lslot = w * 512;                     // wave-uniform LDS elem base

  bf16* Am0 = &lds[0][0][0][0];
  bf16* Am1 = &lds[1][0][0][0];
  bf16* Bm0 = &lds[0][1][0][0];
  bf16* Bm1 = &lds[1][1][0][0];

  auto stage = [&](const bf16* g, bf16* lmat, int half, int kt) {
    const bf16* gs = g + (long)half * 128 * K + (long)kt * 64;
    bf16* ls = lmat + half * 8192 + lslot;
    gl_lds16(gs, ls);
    gl_lds16(gs + 64L * K, ls + 4096);
  };

  // fragment read bases (AS3, swizzled)
  const int lofsA = (wm + r16) * 64;
  const int lofsB = (wn + r16) * 64;
  const int c8x0 = ((0 * 4 + quad) ^ (r16 & 7)) * 8;
  const int c8x1 = ((1 * 4 + quad) ^ (r16 & 7)) * 8;
  lu16* lb = (lu16*)&lds[0][0][0][0];
  lu16* pA0k0 = lb + 0 * 32768 + 0 * 16384 + lofsA + c8x0;
  lu16* pA0k1 = lb + 0 * 32768 + 0 * 16384 + lofsA + c8x1;
  lu16* pA1k0 = lb + 1 * 32768 + 0 * 16384 + lofsA + c8x0;
  lu16* pA1k1 = lb + 1 * 32768 + 0 * 16384 + lofsA + c8x1;
  lu16* pB0k0 = lb + 0 * 32768 + 1 * 16384 + lofsB + c8x0;
  lu16* pB0k1 = lb + 0 * 32768 + 1 * 16384 + lofsB + c8x1;
  lu16* pB1k0 = lb + 1 * 32768 + 1 * 16384 + lofsB + c8x0;
  lu16* pB1k1 = lb + 1 * 32768 + 1 * 16384 + lofsB + c8x1;

  floatx4 acc[8][4];
#pragma unroll
  for (int a = 0; a < 8; a++)
#pragma unroll
    for (int b = 0; b < 4; b++) acc[a][b] = (floatx4){0.f, 0.f, 0.f, 0.f};

  short8 af[4][2], bq0[2][2], bq1[2][2];

// 4 MFMAs: af[MF] (2 k-chunks) x BQ[0..1] -> acc[AR][NB], acc[AR][NB+1]
#define MMAG(AR, MF, NB, BQ) do { \
  acc[AR][NB]     = __builtin_amdgcn_mfma_f32_16x16x32_bf16(af[MF][0], BQ[0][0], acc[AR][NB], 0, 0, 0); \
  acc[AR][NB]     = __builtin_amdgcn_mfma_f32_16x16x32_bf16(af[MF][1], BQ[0][1], acc[AR][NB], 0, 0, 0); \
  acc[AR][NB + 1] = __builtin_amdgcn_mfma_f32_16x16x32_bf16(af[MF][0], BQ[1][0], acc[AR][NB + 1], 0, 0, 0); \
  acc[AR][NB + 1] = __builtin_amdgcn_mfma_f32_16x16x32_bf16(af[MF][1], BQ[1][1], acc[AR][NB + 1], 0, 0, 0); \
} while (0)

// Phase-A issue order: af0(#1-2), bq0(#3-6), af1(#7-8), af2(#9-10), af3(#11-12), bq1(#13-16)
#define ISSUE_PA(PA0, PA1, PB0, PB1) do { \
  af[0][0] = ldsro<0>(PA0);     af[0][1] = ldsro<0>(PA1); \
  bq0[0][0] = ldsro<0>(PB0);    bq0[0][1] = ldsro<0>(PB1); \
  bq0[1][0] = ldsro<2048>(PB0); bq0[1][1] = ldsro<2048>(PB1); \
  af[1][0] = ldsro<2048>(PA0);  af[1][1] = ldsro<2048>(PA1); \
  af[2][0] = ldsro<4096>(PA0);  af[2][1] = ldsro<4096>(PA1); \
  af[3][0] = ldsro<6144>(PA0);  af[3][1] = ldsro<6144>(PA1); \
  bq1[0][0] = ldsro<4096>(PB0); bq1[0][1] = ldsro<4096>(PB1); \
  bq1[1][0] = ldsro<6144>(PB0); bq1[1][1] = ldsro<6144>(PB1); \
} while (0)

// Phase-B issue: af MG1 pairs (#1-2 .. #7-8), offsets (4+mf)*2048
#define ISSUE_PB(PA0, PA1) do { \
  af[0][0] = ldsro<8192>(PA0);  af[0][1] = ldsro<8192>(PA1); \
  af[1][0] = ldsro<10240>(PA0); af[1][1] = ldsro<10240>(PA1); \
  af[2][0] = ldsro<12288>(PA0); af[2][1] = ldsro<12288>(PA1); \
  af[3][0] = ldsro<14336>(PA0); af[3][1] = ldsro<14336>(PA1); \
} while (0)

// one K-tile, 2 phases, 1 barrier each.  SA*/SB* staging stmts; VMX at phB end
#define KTILE(PA0, PA1, PB0, PB1, SA1, SA2, SB1, SB2, VMX) do { \
  /* Phase A: MG0 x {NG0, NG1} */ \
  ISSUE_PA(PA0, PA1, PB0, PB1); SA1; SA2; \
  __builtin_amdgcn_s_setprio(1); \
  WAITLG(10); MMAG(0, 0, 0, bq0); \
  WAITLG(8);  MMAG(1, 1, 0, bq0); \
  WAITLG(6);  MMAG(2, 2, 0, bq0); \
  WAITLG(4);  MMAG(3, 3, 0, bq0); \
  WAITLG(0); \
  MMAG(0, 0, 2, bq1); MMAG(1, 1, 2, bq1); MMAG(2, 2, 2, bq1); MMAG(3, 3, 2, bq1); \
  __builtin_amdgcn_s_setprio(0); BAR(); \
  /* Phase B: MG1 x {NG0, NG1} */ \
  ISSUE_PB(PA0, PA1); SB1; SB2; \
  __builtin_amdgcn_s_setprio(1); \
  WAITLG(6); MMAG(4, 0, 0, bq0); MMAG(4, 0, 2, bq1); \
  WAITLG(4); MMAG(5, 1, 0, bq0); MMAG(5, 1, 2, bq1); \
  WAITLG(2); MMAG(6, 2, 0, bq0); MMAG(6, 2, 2, bq1); \
  WAITLG(0); MMAG(7, 3, 0, bq0); MMAG(7, 3, 2, bq1); \
  __builtin_amdgcn_s_setprio(0); \
  VMX; BAR(); \
} while (0)

  // prologue: tile0 -> buf0 (8 loads), tile1 B -> buf1 (4 loads); drain tile0
  stage(Ag, Am0, 0, 0); stage(Ag, Am0, 1, 0);
  stage(Bg, Bm0, 0, 0); stage(Bg, Bm0, 1, 0);
  stage(Bg, Bm1, 0, 1); stage(Bg, Bm1, 1, 1);
  VMCNT(4);
  BAR();

  // staging calendar per iteration i (tile 2i in buf0, 2i+1 in buf1):
  //  KT(2i):   phA stages A(2i+1)->buf1; phB stages B(2i+2)->buf0; vmcnt(4)
  //  KT(2i+1): phA stages A(2i+2)->buf0; phB stages B(2i+3)->buf1; vmcnt(4)
  const int NI = K >> 7;
  for (int i = 0; i < NI - 1; ++i) {
    const int k1 = 2 * i + 1, k2 = 2 * i + 2, k3 = 2 * i + 3;
    KTILE(pA0k0, pA0k1, pB0k0, pB0k1,
          stage(Ag, Am1, 0, k1), stage(Ag, Am1, 1, k1),
          stage(Bg, Bm0, 0, k2), stage(Bg, Bm0, 1, k2), VMCNT(4));
    KTILE(pA1k0, pA1k1, pB1k0, pB1k1,
          stage(Ag, Am0, 0, k2), stage(Ag, Am0, 1, k2),
          stage(Bg, Bm1, 0, k3), stage(Bg, Bm1, 1, k3), VMCNT(4));
  }
  {
    const int kl = 2 * NI - 1;  // last odd tile: only its A halves remain to stage
    KTILE(pA0k0, pA0k1, pB0k0, pB0k1,
          stage(Ag, Am1, 0, kl), stage(Ag, Am1, 1, kl),
          (void)0, (void)0, VMCNT(0));
    KTILE(pA1k0, pA1k1, pB1k0, pB1k1,
          (void)0, (void)0, (void)0, (void)0, (void)0);
  }

#undef KTILE
#undef ISSUE_PB
#undef ISSUE_PA
#undef MMAG

  // C/D layout: col = lane&15, row = quad*4 + reg
#pragma unroll
  for (int mf = 0; mf < 8; ++mf) {
#pragma unroll
    for (int i2 = 0; i2 < 4; ++i2) {
      long row = bM + wm + mf * 16 + quad * 4 + i2;
      OUT_T* crow = C + row * (long)N + bN + wn + r16;
#pragma unroll
      for (int nf = 0; nf < 4; ++nf) stf(&crow[nf * 16], acc[mf][nf][i2]);
    }
  }
}

// ---------- scan ----------
// c = sigmoid(-gate), v = sigmoid(gate) * g(hidden); g(x) = x>=0 ? x+0.5 : sigmoid(x)
__device__ __forceinline__ void cv_compute(float hval, float gval, float& c, float& v) {
  float eg = __expf(gval);
  c = 1.f / (1.f + eg);
  float z = 1.f - c;
  float gx = (hval >= 0.f) ? (hval + 0.5f) : (1.f / (1.f + __expf(-hval)));
  v = z * gx;
}

// pass1: per (b, chunk, e-quad): P = prod c, V = local recurrence from 0 (4 elems/thread)
__global__ void scan_pass1(const bf16* __restrict__ hg, float* __restrict__ P,
                           float* __restrict__ V, int S, int Di, int NN, int nch) {
  int tid = blockIdx.x * blockDim.x + threadIdx.x;  // over B*nch*(Di/4)
  int De = Di >> 2;
  int e = (tid % De) * 4;
  int rest = tid / De;
  int ch = rest % nch;
  int b = rest / nch;
  int CH = S / nch;
  const bf16* ph = hg + ((long)(b * S + ch * CH)) * NN + e;
  float Pv[4] = {1.f, 1.f, 1.f, 1.f}, Vv[4] = {0.f, 0.f, 0.f, 0.f};
  for (int t = 0; t < CH; t++) {
    float hv[4], gv[4];
    ld4(ph, hv);
    ld4(ph + Di, gv);
#pragma unroll
    for (int j = 0; j < 4; j++) {
      float c, v;
      cv_compute(hv[j], gv[j], c, v);
      Pv[j] *= c;
      Vv[j] = fmaf(c, Vv[j], v);
    }
    ph += NN;
  }
  long base = ((long)(b * nch + ch)) * Di + e;
  *(float4*)&P[base] = make_float4(Pv[0], Pv[1], Pv[2], Pv[3]);
  *(float4*)&V[base] = make_float4(Vv[0], Vv[1], Vv[2], Vv[3]);
}

// pass2: scan the chunk summaries, store carry-in per chunk
__global__ void scan_pass2(const float* __restrict__ P, const float* __restrict__ V,
                           float* __restrict__ Hc, int Di, int nch) {
  int tid = blockIdx.x * blockDim.x + threadIdx.x;  // b*Di + e
  int e = tid % Di;
  int b = tid / Di;
  float H = 0.f;
  for (int j = 0; j < nch; j++) {
    long idx = ((long)(b * nch + j)) * Di + e;
    Hc[idx] = H;
    H = fmaf(P[idx], H, V[idx]);
  }
}

// pass3: replay chunk with carry, write h (bf16), 4 elems/thread
__global__ void scan_pass3(const bf16* __restrict__ hg, const float* __restrict__ Hc,
                           bf16* __restrict__ h, int S, int Di, int NN, int nch) {
  int tid = blockIdx.x * blockDim.x + threadIdx.x;  // over B*nch*(Di/4)
  int De = Di >> 2;
  int e = (tid % De) * 4;
  int rest = tid / De;
  int ch = rest % nch;
  int b = rest / nch;
  int CH = S / nch;
  const bf16* ph = hg + ((long)(b * S + ch * CH)) * NN + e;
  bf16* po = h + ((long)(b * S + ch * CH)) * Di + e;
  long base = ((long)(b * nch + ch)) * Di + e;
  float4 hc = *(const float4*)&Hc[base];
  float H[4] = {hc.x, hc.y, hc.z, hc.w};
  for (int t = 0; t < CH; t++) {
    float hv[4], gv[4];
    ld4(ph, hv);
    ld4(ph + Di, gv);
    ushort4 o;
#pragma unroll
    for (int j = 0; j < 4; j++) {
      float c, v;
      cv_compute(hv[j], gv[j], c, v);
      H[j] = fmaf(c, H[j], v);
    }
    o.x = f2bu(H[0]); o.y = f2bu(H[1]); o.z = f2bu(H[2]); o.w = f2bu(H[3]);
    *(ushort4*)po = o;
    ph += NN;
    po += Di;
  }
}

// ---------- launch ----------
extern "C" void kernel_launch(void* const* d_in, const int* in_sizes, int n_in,
                              void* d_out, int out_size, void* d_ws, size_t ws_size,
                              hipStream_t stream) {
  const int B = 4, S = 4096, D = 2048, Di = 3072, NN = 6144;
  const int Mr = B * S;       // 16384
  const int NCH = 64;         // chunks per sequence (chunk length 64)

  const float* x = (const float*)d_in[0];
  const float* w_hg = (const float*)d_in[1];
  const float* w_out = (const float*)d_in[2];
  float* out = (float*)d_out;

  char* wp = (char*)d_ws;
  bf16* x_bf = (bf16*)wp;  wp += (size_t)Mr * D * 2;        // 67.1 MB
  bf16* whgT = (bf16*)wp;  wp += (size_t)NN * D * 2;        // 25.2 MB
  bf16* woutT = (bf16*)wp; wp += (size_t)D * Di * 2;        // 12.6 MB
  bf16* h_bf = (bf16*)wp;  wp += (size_t)Mr * Di * 2;       // 100.7 MB
  bf16* hg = (bf16*)wp;    wp += (size_t)Mr * NN * 2;       // 201.3 MB

  // P/V/Hc alias the front of x_bf: x_bf is dead after gemm1 reads it, and
  // is fully rewritten by cvt before the next iteration's gemm1. P/V/Hc are
  // written by pass1/2 (after gemm1) and dead after pass3 -- no overlap.
  float* P = (float*)x_bf;                                  // 3.15 MB
  float* V = P + (size_t)B * NCH * Di;                      // 3.15 MB
  float* Hc = V + (size_t)B * NCH * Di;                     // 3.15 MB

  // conversions / transposes
  cvt_f32_bf16<<<(int)(((long)Mr * D / 4 + 255) / 256), 256, 0, stream>>>(x, x_bf, (long)Mr * D / 4);
  transpose_f32_to_bf16<<<dim3(NN / 32, D / 32), 256, 0, stream>>>(w_hg, whgT, D, NN);
  transpose_f32_to_bf16<<<dim3(D / 32, Di / 32), 256, 0, stream>>>(w_out, woutT, Di, D);

  const int nwg1 = (NN / 256) * (Mr / 256);  // 24*64 = 1536
  const int nwg2 = (D / 256) * (Mr / 256);   // 8*64  = 512
  int scan_vthreads = B * NCH * (Di / 4);    // 196608

  gemm256<bf16><<<nwg1, 512, 0, stream>>>(x_bf, whgT, hg, Mr, NN, D);
  scan_pass1<<<scan_vthreads / 256, 256, 0, stream>>>(hg, P, V, S, Di, NN, NCH);
  scan_pass2<<<(B * Di) / 256, 256, 0, stream>>>(P, V, Hc, Di, NCH);
  scan_pass3<<<scan_vthreads / 256, 256, 0, stream>>>(hg, Hc, h_bf, S, Di, NN, NCH);

  gemm256<float><<<nwg2, 512, 0, stream>>>(h_bf, woutT, out, Mr, D, Di);
}